// Round 2
// baseline (856.575 us; speedup 1.0000x reference)
//
#include <hip/hip_runtime.h>
#include <hip/hip_bf16.h>
#include <math.h>

// Problem constants
#define N_TOK 4096
#define C_DIM 1024
#define H_DIM 4096
#define NEXP 7          // dynamic experts
#define NGRP 8          // 7 dynamic + 1 static
#define HCAP 13184      // max padded entries: <=13177, rounded up

typedef __attribute__((ext_vector_type(8))) short short8;
typedef __attribute__((ext_vector_type(4))) float floatx4;

// ---- workspace layout (bytes) ----
static const size_t OFF_COUNTS = 0;                                  // int[8]
static const size_t OFF_CURSOR = 64;                                 // int[8]
static const size_t OFF_BASE   = 128;                                // int[8]
static const size_t OFF_PCOUNT = 192;                                // int[8]
static const size_t OFF_CNT8   = 256;                                // int[8]
static const size_t OFF_USAGE  = 320;                                // float[8]
static const size_t OFF_TOPKI  = 4096;                               // int[8192]
static const size_t OFF_TOPKW  = OFF_TOPKI + 8192ull * 4;            // float[8192]
static const size_t OFF_ETOK   = OFF_TOPKW + 8192ull * 4;            // int[HCAP]
static const size_t OFF_EWT    = OFF_ETOK + (size_t)HCAP * 4;        // float[HCAP]
static const size_t OFF_EIDX   = OFF_EWT + (size_t)HCAP * 4;         // int[8192] token->entry map
static const size_t OFF_XB     = 262144;                             // bf16[N*C]
static const size_t OFF_W1T    = OFF_XB + (size_t)N_TOK * C_DIM * 2; // bf16[8][H][C]; reused as yp after gemm1
static const size_t OFF_W2T    = OFF_W1T + (size_t)NGRP * H_DIM * C_DIM * 2; // bf16[8][C][H]
static const size_t OFF_H      = OFF_W2T + (size_t)NGRP * C_DIM * H_DIM * 2; // bf16[HCAP][H]

static __device__ __forceinline__ unsigned short f2bf(float f) {
    __hip_bfloat16 b = __float2bfloat16(f);
    return *reinterpret_cast<unsigned short*>(&b);
}
static __device__ __forceinline__ float bf2f(unsigned short u) {
    unsigned int v = ((unsigned int)u) << 16;
    return __builtin_bit_cast(float, v);
}

// exact-gelu via A&S 7.1.26 erf approx (|err|<=1.5e-7)
static __device__ __forceinline__ float gelu_f(float v) {
    float z = v * 0.70710678118654752f;
    float az = fabsf(z);
    float t = 1.0f / (1.0f + 0.3275911f * az);
    float poly = t * (0.254829592f + t * (-0.284496736f + t * (1.421413741f +
                 t * (-1.453152027f + t * 1.061405429f))));
    float erf_abs = 1.0f - poly * __expf(-az * az);
    float erf_v = (z < 0.f) ? -erf_abs : erf_abs;
    return 0.5f * v * (1.0f + erf_v);
}

static __device__ __forceinline__ void gll16(const void* g, void* l) {
    __builtin_amdgcn_global_load_lds((const __attribute__((address_space(1))) void*)g,
                                     (__attribute__((address_space(3))) void*)l, 16, 0, 0);
}

// counted vmcnt waits (memory clobber: nothing crosses)
static __device__ __forceinline__ void wait_vm8() { asm volatile("s_waitcnt vmcnt(8)" ::: "memory"); }
static __device__ __forceinline__ void wait_vm4() { asm volatile("s_waitcnt vmcnt(4)" ::: "memory"); }
static __device__ __forceinline__ void wait_vm0() { asm volatile("s_waitcnt vmcnt(0)" ::: "memory"); }
// raw barrier + compiler fence
static __device__ __forceinline__ void barf() {
    __builtin_amdgcn_s_barrier();
    asm volatile("" ::: "memory");
}

// ---------------- small init ----------------
__global__ void init_small_kernel(int* counts, int* cursor, float* usage) {
    int i = threadIdx.x;
    if (i < 8) { counts[i] = 0; cursor[i] = 0; usage[i] = 0.f; }
}

// ---------------- x fp32 -> bf16 ----------------
__global__ void convert_x_kernel(const float* __restrict__ x, unsigned short* __restrict__ xb) {
    int i = blockIdx.x * 256 + threadIdx.x;   // i < N*C/4
    float4 v = ((const float4*)x)[i];
    ushort4 o;
    o.x = f2bf(v.x); o.y = f2bf(v.y); o.z = f2bf(v.z); o.w = f2bf(v.w);
    ((ushort4*)xb)[i] = o;
}

// ---------------- transpose + convert: src[R,S] fp32 -> dst[S,R] bf16, 8 experts ----
__global__ __launch_bounds__(256) void transpose_cvt_kernel(
    const float* __restrict__ dyn, const float* __restrict__ stat,
    __hip_bfloat16* __restrict__ dst, int R, int S)
{
    int e = blockIdx.z;
    const float* src = (e < NEXP) ? (dyn + (size_t)e * R * S) : stat;
    unsigned short* d = (unsigned short*)(dst + (size_t)e * R * S);
    int s0 = blockIdx.x * 32, r0 = blockIdx.y * 64;
    __shared__ float t[64][33];
    int tx4 = threadIdx.x & 15, ty4 = threadIdx.x >> 4;   // 16 x 16
#pragma unroll
    for (int i = 0; i < 4; i++) {
        int r = ty4 + i * 16;
        float2 v = *(const float2*)(src + (size_t)(r0 + r) * S + s0 + tx4 * 2);
        t[r][tx4 * 2] = v.x; t[r][tx4 * 2 + 1] = v.y;
    }
    __syncthreads();
    int tx3 = threadIdx.x & 31, ty3 = threadIdx.x >> 5;   // 32 x 8
#pragma unroll
    for (int i = 0; i < 4; i++) {
        int s = ty3 + i * 8;
        int r = tx3 * 2;
        ushort2 o;
        o.x = f2bf(t[r][s]); o.y = f2bf(t[r + 1][s]);
        *(ushort2*)(d + (size_t)(s0 + s) * R + r0 + r) = o;
    }
}

// ---------------- gating: one wave per token ----------------
__global__ __launch_bounds__(256) void gate_kernel(
    const float* __restrict__ x, const float* __restrict__ gw,
    int* __restrict__ topki, float* __restrict__ topkw,
    int* counts, float* usage)
{
    int wid = threadIdx.x >> 6, lane = threadIdx.x & 63;
    int t = blockIdx.x * 4 + wid;
    float s[NEXP];
#pragma unroll
    for (int e = 0; e < NEXP; e++) s[e] = 0.f;
    for (int c = lane; c < C_DIM; c += 64) {
        float xv = x[(size_t)t * C_DIM + c];
#pragma unroll
        for (int e = 0; e < NEXP; e++) s[e] += xv * gw[c * NEXP + e];
    }
#pragma unroll
    for (int e = 0; e < NEXP; e++)
        for (int off = 32; off > 0; off >>= 1) s[e] += __shfl_xor(s[e], off);
    if (lane == 0) {
        int e0 = 0;
        for (int e = 1; e < NEXP; e++) if (s[e] > s[e0]) e0 = e;
        int e1 = -1;
        for (int e = 0; e < NEXP; e++) {
            if (e == e0) continue;
            if (e1 < 0 || s[e] > s[e1]) e1 = e;
        }
        float w0 = 1.f / (1.f + expf(s[e1] - s[e0]));
        float w1 = 1.f - w0;
        topki[t * 2] = e0; topki[t * 2 + 1] = e1;
        topkw[t * 2] = w0; topkw[t * 2 + 1] = w1;
        atomicAdd(&counts[e0], 1); atomicAdd(&counts[e1], 1);
        atomicAdd(&usage[e0], w0); atomicAdd(&usage[e1], w1);
    }
}

// ---------------- prefix: group bases, pads, static entries, aux loss ----------------
__global__ __launch_bounds__(256) void prefix_kernel(
    const int* counts, const float* usage,
    int* base, int* pcount, int* cnt8,
    int* etok, float* ewt, float* y, int aux_index)
{
    __shared__ int sb[NGRP], sc[NGRP], sp[NGRP];
    if (threadIdx.x == 0) {
        int run = 0;
        for (int g = 0; g < NEXP; g++) {
            int c = counts[g];
            int p = (c + 127) & ~127;
            base[g] = run; pcount[g] = p; cnt8[g] = c;
            sb[g] = run; sc[g] = c; sp[g] = p;
            run += p;
        }
        base[NEXP] = run; pcount[NEXP] = N_TOK; cnt8[NEXP] = N_TOK;
        sb[NEXP] = run; sc[NEXP] = N_TOK; sp[NEXP] = N_TOK;
        // aux = 0.01 * variance(expert_usage)
        float u[NEXP]; float mean = 0.f;
        for (int e = 0; e < NEXP; e++) { u[e] = usage[e] / (float)N_TOK; mean += u[e]; }
        mean /= (float)NEXP;
        float var = 0.f;
        for (int e = 0; e < NEXP; e++) { float dd = u[e] - mean; var += dd * dd; }
        var /= (float)NEXP;
        y[aux_index] = 0.01f * var;
    }
    __syncthreads();
    for (int i = threadIdx.x; i < N_TOK; i += 256) {
        etok[sb[NEXP] + i] = i; ewt[sb[NEXP] + i] = 1.0f;
    }
    for (int g = 0; g < NEXP; g++) {
        for (int i = sc[g] + (int)threadIdx.x; i < sp[g]; i += 256) {
            etok[sb[g] + i] = 0; ewt[sb[g] + i] = 0.f;
        }
    }
}

// ---------------- scatter into compact entry lists (+ inverse map) ----------------
__global__ void scatter_kernel(const int* __restrict__ topki, const float* __restrict__ topkw,
                               const int* __restrict__ base, int* cursor,
                               int* __restrict__ etok, float* __restrict__ ewt,
                               int* __restrict__ eidx)
{
    int i = blockIdx.x * 256 + threadIdx.x;   // < 8192
    int t = i >> 1;
    int e = topki[i];
    float w = topkw[i];
    int pos = atomicAdd(&cursor[e], 1);
    int idx = base[e] + pos;
    etok[idx] = t; ewt[idx] = w;
    eidx[i] = idx;
}

// =====================================================================
// Grouped GEMMs: 256x256 tile, BK=32, 512 threads (8 waves, 2M x 4N),
// per-wave 128x64 output (acc 8x4), 4 LDS buffers (128 KB), depth-3
// prefetch, ONE barrier + counted vmcnt(8) per K-tile (never drains).
// Safety: per tile T: vmcnt(8)->bar->STG(T+3)->reads(T)->MFMA.
//   buf[(T+3)&3] last read at tile T-1; those reads completed before each
//   wave reached the iter-T barrier; stage issued after it -> no race.
// Source chunk sigma(row)=(row>>1)&3 swizzle (proven 0 bank conflicts).
// M-tiles of 256 over 128-granular padding: stores guarded by lr<pcount.
// =====================================================================

#define STG1(T) do { int b_ = (T) & 3; size_t so_ = (size_t)(T) * 64; \
        gll16(pA0 + so_, &Als[b_][w * 1024]); \
        gll16(pA1 + so_, &Als[b_][8192 + w * 1024]); \
        gll16(pB0 + so_, &Bls[b_][w * 1024]); \
        gll16(pB1 + so_, &Bls[b_][8192 + w * 1024]); } while (0)

// ---------------- grouped GEMM1: h = gelu(X @ W1[g]) ----------------
// grid: 4096 = 8 xcd * 16 ct * 32 s; xcd = (g+mt)&7 balanced swizzle.
__global__ __launch_bounds__(512, 2) void gemm1_kernel(
    const __hip_bfloat16* __restrict__ xb,
    const __hip_bfloat16* __restrict__ w1t,   // [8][H][C]
    __hip_bfloat16* __restrict__ h,           // [HCAP][H]
    const int* __restrict__ etok,
    const int* __restrict__ base,
    const int* __restrict__ pcount)
{
    int id = blockIdx.x;
    int xcd = id & 7, rest = id >> 3;
    int ct = rest & 15, s = rest >> 4;        // s in [0,32)
    int g = s & 7;
    int mt = ((xcd - g) & 7) + 8 * (s >> 3);  // (g+mt)&7 == xcd, bijective
    int psz = pcount[g];
    if (mt * 256 >= psz) return;
    int eb = base[g];

    __shared__ __align__(16) char Als[4][16384];
    __shared__ __align__(16) char Bls[4][16384];

    int tid = threadIdx.x, lane = tid & 63, w = tid >> 6;
    int r0 = tid >> 2, c0 = tid & 3;          // staging row (0..127), 16B chunk
    int cs = c0 ^ ((r0 >> 1) & 3);            // sigma same for row and row+128

    int tokA0 = etok[eb + mt * 256 + r0];
    int tokA1 = etok[eb + mt * 256 + 128 + r0];
    const char* pA0 = (const char*)(xb + (size_t)tokA0 * C_DIM) + cs * 16;
    const char* pA1 = (const char*)(xb + (size_t)tokA1 * C_DIM) + cs * 16;
    const char* pB0 = (const char*)(w1t + ((size_t)g * H_DIM + ct * 256 + r0) * C_DIM) + cs * 16;
    const char* pB1 = (const char*)(w1t + ((size_t)g * H_DIM + ct * 256 + 128 + r0) * C_DIM) + cs * 16;

    int wm = w >> 2, wn = w & 3;
    int quad = lane >> 4, l16 = lane & 15;
    int rswz = (quad ^ ((l16 >> 1) & 3)) * 16;

    floatx4 acc[8][4] = {};
    const int NT = C_DIM / 32;                // 32 K-tiles
    STG1(0); STG1(1); STG1(2);
    for (int T = 0; T < NT; ++T) {
        int rem = NT - 1 - T;
        if (rem >= 2) wait_vm8(); else if (rem == 1) wait_vm4(); else wait_vm0();
        barf();
        if (T + 3 < NT) STG1(T + 3);
        const char* Ap = Als[T & 3];
        const char* Bp = Bls[T & 3];
        short8 a[8], b[4];
#pragma unroll
        for (int i = 0; i < 8; i++)
            a[i] = *(const short8*)(Ap + (wm * 128 + i * 16 + l16) * 64 + rswz);
#pragma unroll
        for (int j = 0; j < 4; j++)
            b[j] = *(const short8*)(Bp + (wn * 64 + j * 16 + l16) * 64 + rswz);
        __builtin_amdgcn_s_setprio(1);
#pragma unroll
        for (int i = 0; i < 8; i++)
#pragma unroll
            for (int j = 0; j < 4; j++)
                acc[i][j] = __builtin_amdgcn_mfma_f32_16x16x32_bf16(a[i], b[j], acc[i][j], 0, 0, 0);
        __builtin_amdgcn_s_setprio(0);
    }

    // epilogue: gelu, bf16 store; guard rows beyond group's padded count
#pragma unroll
    for (int i = 0; i < 8; i++) {
        int lr0 = mt * 256 + wm * 128 + i * 16 + quad * 4;
#pragma unroll
        for (int reg = 0; reg < 4; reg++) {
            int lr = lr0 + reg;
            if (lr < psz) {
                size_t hrow = (size_t)(eb + lr) * H_DIM;
#pragma unroll
                for (int j = 0; j < 4; j++) {
                    int cc = ct * 256 + wn * 64 + j * 16 + l16;
                    h[hrow + cc] = __float2bfloat16(gelu_f(acc[i][j][reg]));
                }
            }
        }
    }
}

// ---------------- grouped GEMM2: yp[entry] = H[entry] @ W2[g] ----------------
// grid: 1024 = 8 xcd * 4 ct * 32 s; same swizzle; ct-blocks of a panel share
// the A-panel (h rows) on one XCD -> L2 reuse.
__global__ __launch_bounds__(512, 2) void gemm2_kernel(
    const __hip_bfloat16* __restrict__ h,
    const __hip_bfloat16* __restrict__ w2t,   // [8][C][H]
    unsigned short* __restrict__ yp,          // bf16 [HCAP][C]
    const int* __restrict__ base,
    const int* __restrict__ pcount)
{
    int id = blockIdx.x;
    int xcd = id & 7, rest = id >> 3;
    int ct = rest & 3, s = rest >> 2;         // s in [0,32)
    int g = s & 7;
    int mt = ((xcd - g) & 7) + 8 * (s >> 3);
    int psz = pcount[g];
    if (mt * 256 >= psz) return;
    int eb = base[g];

    __shared__ __align__(16) char Als[4][16384];
    __shared__ __align__(16) char Bls[4][16384];

    int tid = threadIdx.x, lane = tid & 63, w = tid >> 6;
    int r0 = tid >> 2, c0 = tid & 3;
    int cs = c0 ^ ((r0 >> 1) & 3);

    const char* pA0 = (const char*)(h + (size_t)(eb + mt * 256 + r0) * H_DIM) + cs * 16;
    const char* pA1 = (const char*)(h + (size_t)(eb + mt * 256 + 128 + r0) * H_DIM) + cs * 16;
    const char* pB0 = (const char*)(w2t + ((size_t)g * C_DIM + ct * 256 + r0) * H_DIM) + cs * 16;
    const char* pB1 = (const char*)(w2t + ((size_t)g * C_DIM + ct * 256 + 128 + r0) * H_DIM) + cs * 16;

    int wm = w >> 2, wn = w & 3;
    int quad = lane >> 4, l16 = lane & 15;
    int rswz = (quad ^ ((l16 >> 1) & 3)) * 16;

    floatx4 acc[8][4] = {};
    const int NT = H_DIM / 32;                // 128 K-tiles
    STG1(0); STG1(1); STG1(2);
    for (int T = 0; T < NT; ++T) {
        int rem = NT - 1 - T;
        if (rem >= 2) wait_vm8(); else if (rem == 1) wait_vm4(); else wait_vm0();
        barf();
        if (T + 3 < NT) STG1(T + 3);
        const char* Ap = Als[T & 3];
        const char* Bp = Bls[T & 3];
        short8 a[8], b[4];
#pragma unroll
        for (int i = 0; i < 8; i++)
            a[i] = *(const short8*)(Ap + (wm * 128 + i * 16 + l16) * 64 + rswz);
#pragma unroll
        for (int j = 0; j < 4; j++)
            b[j] = *(const short8*)(Bp + (wn * 64 + j * 16 + l16) * 64 + rswz);
        __builtin_amdgcn_s_setprio(1);
#pragma unroll
        for (int i = 0; i < 8; i++)
#pragma unroll
            for (int j = 0; j < 4; j++)
                acc[i][j] = __builtin_amdgcn_mfma_f32_16x16x32_bf16(a[i], b[j], acc[i][j], 0, 0, 0);
        __builtin_amdgcn_s_setprio(0);
    }

#pragma unroll
    for (int i = 0; i < 8; i++) {
        int lr0 = mt * 256 + wm * 128 + i * 16 + quad * 4;
#pragma unroll
        for (int reg = 0; reg < 4; reg++) {
            int lr = lr0 + reg;
            if (lr < psz) {
                size_t yrow = (size_t)(eb + lr) * C_DIM;
#pragma unroll
                for (int j = 0; j < 4; j++) {
                    int cc = ct * 256 + wn * 64 + j * 16 + l16;
                    yp[yrow + cc] = f2bf(acc[i][j][reg]);
                }
            }
        }
    }
}

// ---------------- combine: y[t] = w0*yp[i0] + w1*yp[i1] + yp[static+t] ----------------
__global__ __launch_bounds__(256) void combine_kernel(
    const unsigned short* __restrict__ yp,
    const int* __restrict__ eidx,
    const float* __restrict__ topkw,
    const int* __restrict__ base,
    float* __restrict__ y)
{
    int t = blockIdx.x;
    int i0 = eidx[t * 2], i1 = eidx[t * 2 + 1];
    float w0 = topkw[t * 2], w1 = topkw[t * 2 + 1];
    int is = base[NEXP] + t;
    int c = threadIdx.x * 4;
    ushort4 a = *(const ushort4*)(yp + (size_t)i0 * C_DIM + c);
    ushort4 b = *(const ushort4*)(yp + (size_t)i1 * C_DIM + c);
    ushort4 s = *(const ushort4*)(yp + (size_t)is * C_DIM + c);
    float4 o;
    o.x = w0 * bf2f(a.x) + w1 * bf2f(b.x) + bf2f(s.x);
    o.y = w0 * bf2f(a.y) + w1 * bf2f(b.y) + bf2f(s.y);
    o.z = w0 * bf2f(a.z) + w1 * bf2f(b.z) + bf2f(s.z);
    o.w = w0 * bf2f(a.w) + w1 * bf2f(b.w) + bf2f(s.w);
    *(float4*)(y + (size_t)t * C_DIM + c) = o;
}

extern "C" void kernel_launch(void* const* d_in, const int* in_sizes, int n_in,
                              void* d_out, int out_size, void* d_ws, size_t ws_size,
                              hipStream_t stream) {
    const float* x      = (const float*)d_in[0];
    const float* gate_w = (const float*)d_in[1];
    const float* w1     = (const float*)d_in[2];
    const float* w2     = (const float*)d_in[3];
    const float* w1s    = (const float*)d_in[4];
    const float* w2s    = (const float*)d_in[5];
    float* y = (float*)d_out;
    char* ws = (char*)d_ws;

    int*   counts = (int*)(ws + OFF_COUNTS);
    int*   cursor = (int*)(ws + OFF_CURSOR);
    int*   base   = (int*)(ws + OFF_BASE);
    int*   pcount = (int*)(ws + OFF_PCOUNT);
    int*   cnt8   = (int*)(ws + OFF_CNT8);
    float* usage  = (float*)(ws + OFF_USAGE);
    int*   topki  = (int*)(ws + OFF_TOPKI);
    float* topkw  = (float*)(ws + OFF_TOPKW);
    int*   etok   = (int*)(ws + OFF_ETOK);
    float* ewt    = (float*)(ws + OFF_EWT);
    int*   eidx   = (int*)(ws + OFF_EIDX);
    unsigned short* xb_u = (unsigned short*)(ws + OFF_XB);
    __hip_bfloat16* xb  = (__hip_bfloat16*)(ws + OFF_XB);
    __hip_bfloat16* w1t = (__hip_bfloat16*)(ws + OFF_W1T);
    __hip_bfloat16* w2t = (__hip_bfloat16*)(ws + OFF_W2T);
    __hip_bfloat16* hbuf = (__hip_bfloat16*)(ws + OFF_H);
    unsigned short* yp  = (unsigned short*)(ws + OFF_W1T);  // aliases w1t (dead after gemm1)

    init_small_kernel<<<1, 64, 0, stream>>>(counts, cursor, usage);

    convert_x_kernel<<<(N_TOK * C_DIM / 4) / 256, 256, 0, stream>>>(x, xb_u);
    transpose_cvt_kernel<<<dim3(H_DIM / 32, C_DIM / 64, NGRP), 256, 0, stream>>>(w1, w1s, w1t, C_DIM, H_DIM);
    transpose_cvt_kernel<<<dim3(C_DIM / 32, H_DIM / 64, NGRP), 256, 0, stream>>>(w2, w2s, w2t, H_DIM, C_DIM);

    gate_kernel<<<N_TOK / 4, 256, 0, stream>>>(x, gate_w, topki, topkw, counts, usage);
    prefix_kernel<<<1, 256, 0, stream>>>(counts, usage, base, pcount, cnt8, etok, ewt, y, N_TOK * C_DIM);
    scatter_kernel<<<(N_TOK * 2) / 256, 256, 0, stream>>>(topki, topkw, base, cursor, etok, ewt, eidx);

    gemm1_kernel<<<4096, 512, 0, stream>>>(xb, w1t, hbuf, etok, base, pcount);
    gemm2_kernel<<<1024, 512, 0, stream>>>(hbuf, w2t, yp, base, pcount);
    combine_kernel<<<N_TOK, 256, 0, stream>>>(yp, eidx, topkw, base, y);
}

// Round 3
// 726.665 us; speedup vs baseline: 1.1788x; 1.1788x over previous
//
#include <hip/hip_runtime.h>
#include <hip/hip_bf16.h>
#include <math.h>

// Problem constants
#define N_TOK 4096
#define C_DIM 1024
#define H_DIM 4096
#define NEXP 7          // dynamic experts
#define NGRP 8          // 7 dynamic + 1 static
#define HCAP 13184      // max padded entries: <=13177, rounded up

typedef __attribute__((ext_vector_type(8))) short short8;
typedef __attribute__((ext_vector_type(4))) float floatx4;

// ---- workspace layout (bytes) ----
static const size_t OFF_COUNTS = 0;                                  // int[8]
static const size_t OFF_CURSOR = 64;                                 // int[8]
static const size_t OFF_BASE   = 128;                                // int[8]
static const size_t OFF_PCOUNT = 192;                                // int[8]
static const size_t OFF_CNT8   = 256;                                // int[8]
static const size_t OFF_USAGE  = 320;                                // float[8]
static const size_t OFF_TOPKI  = 4096;                               // int[8192]
static const size_t OFF_TOPKW  = OFF_TOPKI + 8192ull * 4;            // float[8192]
static const size_t OFF_ETOK   = OFF_TOPKW + 8192ull * 4;            // int[HCAP]
static const size_t OFF_EWT    = OFF_ETOK + (size_t)HCAP * 4;        // float[HCAP]
static const size_t OFF_EIDX   = OFF_EWT + (size_t)HCAP * 4;         // int[8192] token->entry map
static const size_t OFF_XB     = 262144;                             // bf16[N*C]
static const size_t OFF_W1T    = OFF_XB + (size_t)N_TOK * C_DIM * 2; // bf16[8][H][C]; reused as yp after gemm1
static const size_t OFF_W2T    = OFF_W1T + (size_t)NGRP * H_DIM * C_DIM * 2; // bf16[8][C][H]
static const size_t OFF_H      = OFF_W2T + (size_t)NGRP * C_DIM * H_DIM * 2; // bf16[HCAP][H]

static __device__ __forceinline__ unsigned short f2bf(float f) {
    __hip_bfloat16 b = __float2bfloat16(f);
    return *reinterpret_cast<unsigned short*>(&b);
}
static __device__ __forceinline__ float bf2f(unsigned short u) {
    unsigned int v = ((unsigned int)u) << 16;
    return __builtin_bit_cast(float, v);
}

// exact-gelu via A&S 7.1.26 erf approx (|err|<=1.5e-7)
static __device__ __forceinline__ float gelu_f(float v) {
    float z = v * 0.70710678118654752f;
    float az = fabsf(z);
    float t = 1.0f / (1.0f + 0.3275911f * az);
    float poly = t * (0.254829592f + t * (-0.284496736f + t * (1.421413741f +
                 t * (-1.453152027f + t * 1.061405429f))));
    float erf_abs = 1.0f - poly * __expf(-az * az);
    float erf_v = (z < 0.f) ? -erf_abs : erf_abs;
    return 0.5f * v * (1.0f + erf_v);
}

static __device__ __forceinline__ void gll16(const void* g, void* l) {
    __builtin_amdgcn_global_load_lds((const __attribute__((address_space(1))) void*)g,
                                     (__attribute__((address_space(3))) void*)l, 16, 0, 0);
}

static __device__ __forceinline__ void barf() {
    __builtin_amdgcn_s_barrier();
    asm volatile("" ::: "memory");
}
// rule #18: lgkmcnt(0) must be followed by sched_barrier(0) so MFMAs can't hoist past it
static __device__ __forceinline__ void lgkm0s() {
    asm volatile("s_waitcnt lgkmcnt(0)" ::: "memory");
    __builtin_amdgcn_sched_barrier(0);
}

// ---------------- small init ----------------
__global__ void init_small_kernel(int* counts, int* cursor, float* usage) {
    int i = threadIdx.x;
    if (i < 8) { counts[i] = 0; cursor[i] = 0; usage[i] = 0.f; }
}

// ---------------- transpose + convert: src[R,S] fp32 -> dst[S,R] bf16, 8 experts ----
// 64x64 tile; float4 loads (256B/row), ushort4 stores (128B/row)
__global__ __launch_bounds__(256) void transpose_cvt_kernel(
    const float* __restrict__ dyn, const float* __restrict__ stat,
    __hip_bfloat16* __restrict__ dst, int R, int S)
{
    int e = blockIdx.z;
    const float* src = (e < NEXP) ? (dyn + (size_t)e * R * S) : stat;
    unsigned short* d = (unsigned short*)(dst + (size_t)e * R * S);
    int s0 = blockIdx.x * 64, r0 = blockIdx.y * 64;
    __shared__ float t[64][65];
    int lx = (threadIdx.x & 15) * 4, ty = threadIdx.x >> 4;   // 16 x 16
#pragma unroll
    for (int i = 0; i < 4; i++) {
        int r = ty + i * 16;
        float4 v = *(const float4*)(src + (size_t)(r0 + r) * S + s0 + lx);
        t[r][lx] = v.x; t[r][lx + 1] = v.y; t[r][lx + 2] = v.z; t[r][lx + 3] = v.w;
    }
    __syncthreads();
#pragma unroll
    for (int i = 0; i < 4; i++) {
        int ss = ty + i * 16;
        ushort4 o;
        o.x = f2bf(t[lx][ss]); o.y = f2bf(t[lx + 1][ss]);
        o.z = f2bf(t[lx + 2][ss]); o.w = f2bf(t[lx + 3][ss]);
        *(ushort4*)(d + (size_t)(s0 + ss) * R + r0 + lx) = o;
    }
}

// ---------------- gating (fused x fp32->bf16 convert): one wave per token ----------------
__global__ __launch_bounds__(256) void gate_kernel(
    const float* __restrict__ x, const float* __restrict__ gw,
    unsigned short* __restrict__ xb,
    int* __restrict__ topki, float* __restrict__ topkw,
    int* counts, float* usage)
{
    int wid = threadIdx.x >> 6, lane = threadIdx.x & 63;
    int t = blockIdx.x * 4 + wid;
    float s[NEXP];
#pragma unroll
    for (int e = 0; e < NEXP; e++) s[e] = 0.f;
#pragma unroll
    for (int it = 0; it < 4; ++it) {
        int c = it * 256 + lane * 4;
        float4 xv = *(const float4*)(x + (size_t)t * C_DIM + c);
        ushort4 o;
        o.x = f2bf(xv.x); o.y = f2bf(xv.y); o.z = f2bf(xv.z); o.w = f2bf(xv.w);
        *(ushort4*)(xb + (size_t)t * C_DIM + c) = o;
        const float* g0 = gw + (size_t)c * NEXP;
#pragma unroll
        for (int e = 0; e < NEXP; e++) s[e] += xv.x * g0[e];
#pragma unroll
        for (int e = 0; e < NEXP; e++) s[e] += xv.y * g0[NEXP + e];
#pragma unroll
        for (int e = 0; e < NEXP; e++) s[e] += xv.z * g0[2 * NEXP + e];
#pragma unroll
        for (int e = 0; e < NEXP; e++) s[e] += xv.w * g0[3 * NEXP + e];
    }
#pragma unroll
    for (int e = 0; e < NEXP; e++)
        for (int off = 32; off > 0; off >>= 1) s[e] += __shfl_xor(s[e], off);
    if (lane == 0) {
        int e0 = 0;
        for (int e = 1; e < NEXP; e++) if (s[e] > s[e0]) e0 = e;
        int e1 = -1;
        for (int e = 0; e < NEXP; e++) {
            if (e == e0) continue;
            if (e1 < 0 || s[e] > s[e1]) e1 = e;
        }
        float w0 = 1.f / (1.f + expf(s[e1] - s[e0]));
        float w1 = 1.f - w0;
        topki[t * 2] = e0; topki[t * 2 + 1] = e1;
        topkw[t * 2] = w0; topkw[t * 2 + 1] = w1;
        atomicAdd(&counts[e0], 1); atomicAdd(&counts[e1], 1);
        atomicAdd(&usage[e0], w0); atomicAdd(&usage[e1], w1);
    }
}

// ---------------- prefix: group bases, pads, static entries, aux loss ----------------
__global__ __launch_bounds__(256) void prefix_kernel(
    const int* counts, const float* usage,
    int* base, int* pcount, int* cnt8,
    int* etok, float* ewt, float* y, int aux_index)
{
    __shared__ int sb[NGRP], sc[NGRP], sp[NGRP];
    if (threadIdx.x == 0) {
        int run = 0;
        for (int g = 0; g < NEXP; g++) {
            int c = counts[g];
            int p = (c + 127) & ~127;
            base[g] = run; pcount[g] = p; cnt8[g] = c;
            sb[g] = run; sc[g] = c; sp[g] = p;
            run += p;
        }
        base[NEXP] = run; pcount[NEXP] = N_TOK; cnt8[NEXP] = N_TOK;
        sb[NEXP] = run; sc[NEXP] = N_TOK; sp[NEXP] = N_TOK;
        float u[NEXP]; float mean = 0.f;
        for (int e = 0; e < NEXP; e++) { u[e] = usage[e] / (float)N_TOK; mean += u[e]; }
        mean /= (float)NEXP;
        float var = 0.f;
        for (int e = 0; e < NEXP; e++) { float dd = u[e] - mean; var += dd * dd; }
        var /= (float)NEXP;
        y[aux_index] = 0.01f * var;
    }
    __syncthreads();
    for (int i = threadIdx.x; i < N_TOK; i += 256) {
        etok[sb[NEXP] + i] = i; ewt[sb[NEXP] + i] = 1.0f;
    }
    for (int g = 0; g < NEXP; g++) {
        for (int i = sc[g] + (int)threadIdx.x; i < sp[g]; i += 256) {
            etok[sb[g] + i] = 0; ewt[sb[g] + i] = 0.f;
        }
    }
}

// ---------------- scatter into compact entry lists (+ inverse map) ----------------
__global__ void scatter_kernel(const int* __restrict__ topki, const float* __restrict__ topkw,
                               const int* __restrict__ base, int* cursor,
                               int* __restrict__ etok, float* __restrict__ ewt,
                               int* __restrict__ eidx)
{
    int i = blockIdx.x * 256 + threadIdx.x;   // < 8192
    int t = i >> 1;
    int e = topki[i];
    float w = topkw[i];
    int pos = atomicAdd(&cursor[e], 1);
    int idx = base[e] + pos;
    etok[idx] = t; ewt[idx] = w;
    eidx[i] = idx;
}

// =====================================================================
// 8-phase grouped GEMM core (m201-style port, plain HIP).
// Tile 256x256, BK=64, 512 thr (8 waves, 2M x 4N), per-wave 128x64.
// LDS 128KB: A [2dbuf][2half][128u][64k], B likewise at +64KB.
//   A half h = M-sub-half rows {wm*128 + h*64 ..+64} (unit u = wm*64+r)
//   B half n = N-half rows {wn*64 + n*32 ..+32}     (unit u = wn*32+r)
// Per K-tile T (dbuf=T&1), 4 quadrant phases:
//   q0 (Mh0,N0): read aM0(8)+bN0(4); stage B-n1(T+1)->dbuf^1
//   q1 (Mh1,N0): read aM1(8);        stage A-h0(T+2)->dbuf
//   q2 (Mh0,N1): read bN1(4);        stage A-h1(T+2)->dbuf
//   q3 (Mh1,N1): no reads;           stage B-n0(T+2)->dbuf
// Each phase: reads|stage -> barrier -> lgkmcnt(0)+sched_barrier ->
//   setprio(1) 16 MFMA setprio(0) -> barrier.  vmcnt(6) once per K-tile
//   (at q3, before its end barrier); vmcnt(0) only in the last 2 tiles.
// Race-audit: every LDS region is lgkm0+barrier-drained before restage;
// every staged unit is vmcnt-retired + barrier'd before first read.
// Source chunk sigma(u)=(u&7) XOR swizzle -> conflict-free ds_read_b128.
// =====================================================================

static __device__ __forceinline__ void mfma16(const short8 (&a)[8], const short8 (&b)[4],
                                              floatx4 (&acc)[8][4], int mo, int no) {
#pragma unroll
    for (int i = 0; i < 4; i++)
#pragma unroll
        for (int j = 0; j < 2; j++)
#pragma unroll
            for (int kk = 0; kk < 2; kk++)
                acc[mo + i][no + j] = __builtin_amdgcn_mfma_f32_16x16x32_bf16(
                    a[i * 2 + kk], b[j * 2 + kk], acc[mo + i][no + j], 0, 0, 0);
}
static __device__ __forceinline__ void rdA(short8 (&d)[8], const char* b, int sw0, int sw1) {
#pragma unroll
    for (int i = 0; i < 4; i++) {
        d[i * 2]     = *(const short8*)(b + i * 2048 + sw0);
        d[i * 2 + 1] = *(const short8*)(b + i * 2048 + sw1);
    }
}
static __device__ __forceinline__ void rdB(short8 (&d)[4], const char* b, int sw0, int sw1) {
#pragma unroll
    for (int j = 0; j < 2; j++) {
        d[j * 2]     = *(const short8*)(b + j * 2048 + sw0);
        d[j * 2 + 1] = *(const short8*)(b + j * 2048 + sw1);
    }
}

static __device__ __forceinline__ void gemm_core(char* lds, int NKT,
    const char* pA0, const char* pA1, const char* pA2, const char* pA3,
    const char* pB0, const char* pB1, const char* pB2, const char* pB3,
    floatx4 (&acc)[8][4])
{
    int tid = threadIdx.x, lane = tid & 63, w = tid >> 6;
    int wm = w >> 2, wn = w & 3, l16 = lane & 15, quad = lane >> 4;
    int sw0 = ((quad ^ (l16 & 7)) << 4);
    int sw1 = (((4 + quad) ^ (l16 & 7)) << 4);
    int aoff = (wm * 64 + l16) * 128;
    int boff = (wn * 32 + l16) * 128;
    int wb = w * 1024;
    short8 aM0[8], aM1[8], bN0[4], bN1[4];

#define SA_(h, doff, ko) do { \
    gll16(((h) ? pA1 : pA0) + (ko), lds + (doff) + (h) * 16384 + wb); \
    gll16(((h) ? pA3 : pA2) + (ko), lds + (doff) + (h) * 16384 + 8192 + wb); } while (0)
#define SB_(nh, doff, ko) do { \
    gll16(((nh) ? pB1 : pB0) + (ko), lds + 65536 + (doff) + (nh) * 16384 + wb); \
    gll16(((nh) ? pB3 : pB2) + (ko), lds + 65536 + (doff) + (nh) * 16384 + 8192 + wb); } while (0)

    // prologue: Kt0 full (dbuf0) + Kt1 {Ah0,Ah1,Bn0} (dbuf1); Bn1(1) staged at T=0 q0
    SA_(0, 0, 0); SA_(1, 0, 0); SB_(0, 0, 0); SB_(1, 0, 0);
    SA_(0, 32768, 128); SA_(1, 32768, 128); SB_(0, 32768, 128);
    asm volatile("s_waitcnt vmcnt(6)" ::: "memory");   // Kt0's 4 units retired; 3 in flight
    barf();

#pragma unroll 1
    for (int T = 0; T < NKT; ++T) {
        int curo = (T & 1) << 15;
        int nxto = curo ^ 32768;
        bool st1 = (T + 1 < NKT), st2 = (T + 2 < NKT);
        // ---- q0 ----
        rdA(aM0, lds + curo + aoff, sw0, sw1);
        rdB(bN0, lds + 65536 + curo + boff, sw0, sw1);
        if (st1) SB_(1, nxto, 128);
        barf(); lgkm0s();
        __builtin_amdgcn_s_setprio(1); mfma16(aM0, bN0, acc, 0, 0); __builtin_amdgcn_s_setprio(0);
        barf();
        // ---- q1 ----
        rdA(aM1, lds + curo + 16384 + aoff, sw0, sw1);
        if (st2) SA_(0, curo, 256);
        barf(); lgkm0s();
        __builtin_amdgcn_s_setprio(1); mfma16(aM1, bN0, acc, 4, 0); __builtin_amdgcn_s_setprio(0);
        barf();
        // ---- q2 ----
        rdB(bN1, lds + 65536 + curo + 16384 + boff, sw0, sw1);
        if (st2) SA_(1, curo, 256);
        barf(); lgkm0s();
        __builtin_amdgcn_s_setprio(1); mfma16(aM0, bN1, acc, 0, 2); __builtin_amdgcn_s_setprio(0);
        barf();
        // ---- q3 ----
        if (st2) SB_(0, curo, 256);
        barf();
        __builtin_amdgcn_s_setprio(1); mfma16(aM1, bN1, acc, 4, 2); __builtin_amdgcn_s_setprio(0);
        if (T >= NKT - 2) { asm volatile("s_waitcnt vmcnt(0)" ::: "memory"); }
        else              { asm volatile("s_waitcnt vmcnt(6)" ::: "memory"); }
        barf();
        pA0 += 128; pA1 += 128; pA2 += 128; pA3 += 128;
        pB0 += 128; pB1 += 128; pB2 += 128; pB3 += 128;
    }
#undef SA_
#undef SB_
}

// ---------------- grouped GEMM1: h = gelu(X @ W1[g]) ----------------
// grid: 4096 = 8 xcd * 16 ct * 32 s; xcd = (g+mt)&7 balanced swizzle.
__global__ __launch_bounds__(512, 2) void gemm1_kernel(
    const __hip_bfloat16* __restrict__ xb,
    const __hip_bfloat16* __restrict__ w1t,   // [8][H][C]
    __hip_bfloat16* __restrict__ h,           // [HCAP][H]
    const int* __restrict__ etok,
    const int* __restrict__ base,
    const int* __restrict__ pcount)
{
    int id = blockIdx.x;
    int xcd = id & 7, rest = id >> 3;
    int ct = rest & 15, s = rest >> 4;        // s in [0,32)
    int g = s & 7;
    int mt = ((xcd - g) & 7) + 8 * (s >> 3);
    int psz = pcount[g];
    if (mt * 256 >= psz) return;
    int eb = base[g];

    __shared__ __align__(16) char lds[131072];

    int tid = threadIdx.x, lane = tid & 63, w = tid >> 6;
    int u0 = 8 * w + (lane >> 3);                      // staging unit row [0,64)
    int v  = (u0 & 31) + ((u0 >> 5) << 6);             // B row helper
    int ssw = ((lane & 7) ^ (lane >> 3)) * 16;         // source chunk swizzle (bytes)

    int t0 = etok[eb + mt * 256 + u0];
    int t1 = etok[eb + mt * 256 + 64 + u0];
    int t2 = etok[eb + mt * 256 + 128 + u0];
    int t3 = etok[eb + mt * 256 + 192 + u0];
    const char* pA0 = (const char*)(xb + (size_t)t0 * C_DIM) + ssw;
    const char* pA1 = (const char*)(xb + (size_t)t1 * C_DIM) + ssw;
    const char* pA2 = (const char*)(xb + (size_t)t2 * C_DIM) + ssw;
    const char* pA3 = (const char*)(xb + (size_t)t3 * C_DIM) + ssw;
    const char* pB0 = (const char*)(w1t + ((size_t)g * H_DIM + ct * 256 + v) * C_DIM) + ssw;
    const char* pB1 = (const char*)(w1t + ((size_t)g * H_DIM + ct * 256 + v + 32) * C_DIM) + ssw;
    const char* pB2 = (const char*)(w1t + ((size_t)g * H_DIM + ct * 256 + v + 128) * C_DIM) + ssw;
    const char* pB3 = (const char*)(w1t + ((size_t)g * H_DIM + ct * 256 + v + 160) * C_DIM) + ssw;

    floatx4 acc[8][4] = {};
    gemm_core(lds, C_DIM / 64, pA0, pA1, pA2, pA3, pB0, pB1, pB2, pB3, acc);

    int wm = w >> 2, wn = w & 3, l16 = lane & 15, quad = lane >> 4;
#pragma unroll
    for (int i = 0; i < 8; i++) {
        int lr0 = mt * 256 + wm * 128 + i * 16 + quad * 4;
#pragma unroll
        for (int reg = 0; reg < 4; reg++) {
            int lr = lr0 + reg;
            if (lr < psz) {
                size_t hrow = (size_t)(eb + lr) * H_DIM;
#pragma unroll
                for (int j = 0; j < 4; j++) {
                    int cc = ct * 256 + wn * 64 + j * 16 + l16;
                    h[hrow + cc] = __float2bfloat16(gelu_f(acc[i][j][reg]));
                }
            }
        }
    }
}

// ---------------- grouped GEMM2: yp[entry] = H[entry] @ W2[g] ----------------
// grid: 1024 = 8 xcd * 4 ct * 32 s; same swizzle; ct-blocks of one A-panel
// co-locate on one XCD -> L2 reuse of h.
__global__ __launch_bounds__(512, 2) void gemm2_kernel(
    const __hip_bfloat16* __restrict__ h,
    const __hip_bfloat16* __restrict__ w2t,   // [8][C][H]
    unsigned short* __restrict__ yp,          // bf16 [HCAP][C]
    const int* __restrict__ base,
    const int* __restrict__ pcount)
{
    int id = blockIdx.x;
    int xcd = id & 7, rest = id >> 3;
    int ct = rest & 3, s = rest >> 2;         // s in [0,32)
    int g = s & 7;
    int mt = ((xcd - g) & 7) + 8 * (s >> 3);
    int psz = pcount[g];
    if (mt * 256 >= psz) return;
    int eb = base[g];

    __shared__ __align__(16) char lds[131072];

    int tid = threadIdx.x, lane = tid & 63, w = tid >> 6;
    int u0 = 8 * w + (lane >> 3);
    int v  = (u0 & 31) + ((u0 >> 5) << 6);
    int ssw = ((lane & 7) ^ (lane >> 3)) * 16;

    const char* pA0 = (const char*)(h + (size_t)(eb + mt * 256 + u0) * H_DIM) + ssw;
    const char* pA1 = (const char*)(h + (size_t)(eb + mt * 256 + 64 + u0) * H_DIM) + ssw;
    const char* pA2 = (const char*)(h + (size_t)(eb + mt * 256 + 128 + u0) * H_DIM) + ssw;
    const char* pA3 = (const char*)(h + (size_t)(eb + mt * 256 + 192 + u0) * H_DIM) + ssw;
    const char* pB0 = (const char*)(w2t + ((size_t)g * C_DIM + ct * 256 + v) * H_DIM) + ssw;
    const char* pB1 = (const char*)(w2t + ((size_t)g * C_DIM + ct * 256 + v + 32) * H_DIM) + ssw;
    const char* pB2 = (const char*)(w2t + ((size_t)g * C_DIM + ct * 256 + v + 128) * H_DIM) + ssw;
    const char* pB3 = (const char*)(w2t + ((size_t)g * C_DIM + ct * 256 + v + 160) * H_DIM) + ssw;

    floatx4 acc[8][4] = {};
    gemm_core(lds, H_DIM / 64, pA0, pA1, pA2, pA3, pB0, pB1, pB2, pB3, acc);

    int wm = w >> 2, wn = w & 3, l16 = lane & 15, quad = lane >> 4;
#pragma unroll
    for (int i = 0; i < 8; i++) {
        int lr0 = mt * 256 + wm * 128 + i * 16 + quad * 4;
#pragma unroll
        for (int reg = 0; reg < 4; reg++) {
            int lr = lr0 + reg;
            if (lr < psz) {
                size_t yrow = (size_t)(eb + lr) * C_DIM;
#pragma unroll
                for (int j = 0; j < 4; j++) {
                    int cc = ct * 256 + wn * 64 + j * 16 + l16;
                    yp[yrow + cc] = f2bf(acc[i][j][reg]);
                }
            }
        }
    }
}

// ---------------- combine: y[t] = w0*yp[i0] + w1*yp[i1] + yp[static+t] ----------------
__global__ __launch_bounds__(256) void combine_kernel(
    const unsigned short* __restrict__ yp,
    const int* __restrict__ eidx,
    const float* __restrict__ topkw,
    const int* __restrict__ base,
    float* __restrict__ y)
{
    int t = blockIdx.x;
    int i0 = eidx[t * 2], i1 = eidx[t * 2 + 1];
    float w0 = topkw[t * 2], w1 = topkw[t * 2 + 1];
    int is = base[NEXP] + t;
    int c = threadIdx.x * 4;
    ushort4 a = *(const ushort4*)(yp + (size_t)i0 * C_DIM + c);
    ushort4 b = *(const ushort4*)(yp + (size_t)i1 * C_DIM + c);
    ushort4 s = *(const ushort4*)(yp + (size_t)is * C_DIM + c);
    float4 o;
    o.x = w0 * bf2f(a.x) + w1 * bf2f(b.x) + bf2f(s.x);
    o.y = w0 * bf2f(a.y) + w1 * bf2f(b.y) + bf2f(s.y);
    o.z = w0 * bf2f(a.z) + w1 * bf2f(b.z) + bf2f(s.z);
    o.w = w0 * bf2f(a.w) + w1 * bf2f(b.w) + bf2f(s.w);
    *(float4*)(y + (size_t)t * C_DIM + c) = o;
}

extern "C" void kernel_launch(void* const* d_in, const int* in_sizes, int n_in,
                              void* d_out, int out_size, void* d_ws, size_t ws_size,
                              hipStream_t stream) {
    const float* x      = (const float*)d_in[0];
    const float* gate_w = (const float*)d_in[1];
    const float* w1     = (const float*)d_in[2];
    const float* w2     = (const float*)d_in[3];
    const float* w1s    = (const float*)d_in[4];
    const float* w2s    = (const float*)d_in[5];
    float* y = (float*)d_out;
    char* ws = (char*)d_ws;

    int*   counts = (int*)(ws + OFF_COUNTS);
    int*   cursor = (int*)(ws + OFF_CURSOR);
    int*   base   = (int*)(ws + OFF_BASE);
    int*   pcount = (int*)(ws + OFF_PCOUNT);
    int*   cnt8   = (int*)(ws + OFF_CNT8);
    float* usage  = (float*)(ws + OFF_USAGE);
    int*   topki  = (int*)(ws + OFF_TOPKI);
    float* topkw  = (float*)(ws + OFF_TOPKW);
    int*   etok   = (int*)(ws + OFF_ETOK);
    float* ewt    = (float*)(ws + OFF_EWT);
    int*   eidx   = (int*)(ws + OFF_EIDX);
    unsigned short* xb_u = (unsigned short*)(ws + OFF_XB);
    __hip_bfloat16* xb  = (__hip_bfloat16*)(ws + OFF_XB);
    __hip_bfloat16* w1t = (__hip_bfloat16*)(ws + OFF_W1T);
    __hip_bfloat16* w2t = (__hip_bfloat16*)(ws + OFF_W2T);
    __hip_bfloat16* hbuf = (__hip_bfloat16*)(ws + OFF_H);
    unsigned short* yp  = (unsigned short*)(ws + OFF_W1T);  // aliases w1t (dead after gemm1)

    init_small_kernel<<<1, 64, 0, stream>>>(counts, cursor, usage);

    // w1 [C,H] -> w1t [H,C]; w1s likewise as expert 7
    transpose_cvt_kernel<<<dim3(H_DIM / 64, C_DIM / 64, NGRP), 256, 0, stream>>>(w1, w1s, w1t, C_DIM, H_DIM);
    // w2 [H,C] -> w2t [C,H]; w2s likewise as expert 7
    transpose_cvt_kernel<<<dim3(C_DIM / 64, H_DIM / 64, NGRP), 256, 0, stream>>>(w2, w2s, w2t, H_DIM, C_DIM);

    gate_kernel<<<N_TOK / 4, 256, 0, stream>>>(x, gate_w, xb_u, topki, topkw, counts, usage);
    prefix_kernel<<<1, 256, 0, stream>>>(counts, usage, base, pcount, cnt8, etok, ewt, y, N_TOK * C_DIM);
    scatter_kernel<<<(N_TOK * 2) / 256, 256, 0, stream>>>(topki, topkw, base, cursor, etok, ewt, eidx);

    gemm1_kernel<<<4096, 512, 0, stream>>>(xb, w1t, hbuf, etok, base, pcount);
    gemm2_kernel<<<1024, 512, 0, stream>>>(hbuf, w2t, yp, base, pcount);
    combine_kernel<<<N_TOK, 256, 0, stream>>>(yp, eidx, topkw, base, y);
}

// Round 4
// 712.225 us; speedup vs baseline: 1.2027x; 1.0203x over previous
//
#include <hip/hip_runtime.h>
#include <hip/hip_bf16.h>
#include <math.h>

// Problem constants
#define N_TOK 4096
#define C_DIM 1024
#define H_DIM 4096
#define NEXP 7          // dynamic experts
#define NGRP 8          // 7 dynamic + 1 static
#define HCAP 13184      // max padded entries: <=13177, rounded up

typedef __attribute__((ext_vector_type(8))) short short8;
typedef __attribute__((ext_vector_type(4))) float floatx4;

// ---- workspace layout (bytes) ----
static const size_t OFF_COUNTS = 0;                                  // int[8]
static const size_t OFF_CURSOR = 64;                                 // int[8]
static const size_t OFF_BASE   = 128;                                // int[8]
static const size_t OFF_PCOUNT = 192;                                // int[8]
static const size_t OFF_CNT8   = 256;                                // int[8]
static const size_t OFF_USAGE  = 320;                                // float[8]
static const size_t OFF_TOPKI  = 4096;                               // int[8192]
static const size_t OFF_TOPKW  = OFF_TOPKI + 8192ull * 4;            // float[8192]
static const size_t OFF_ETOK   = OFF_TOPKW + 8192ull * 4;            // int[HCAP]
static const size_t OFF_EWT    = OFF_ETOK + (size_t)HCAP * 4;        // float[HCAP]
static const size_t OFF_EIDX   = OFF_EWT + (size_t)HCAP * 4;         // int[8192] token->entry map
static const size_t OFF_XB     = 262144;                             // bf16[N*C]
static const size_t OFF_W1T    = OFF_XB + (size_t)N_TOK * C_DIM * 2; // bf16[8][H][C]; reused as yp after gemm1
static const size_t OFF_W2T    = OFF_W1T + (size_t)NGRP * H_DIM * C_DIM * 2; // bf16[8][C][H]
static const size_t OFF_H      = OFF_W2T + (size_t)NGRP * C_DIM * H_DIM * 2; // bf16[HCAP][H]

static __device__ __forceinline__ unsigned short f2bf(float f) {
    __hip_bfloat16 b = __float2bfloat16(f);
    return *reinterpret_cast<unsigned short*>(&b);
}
static __device__ __forceinline__ float bf2f(unsigned short u) {
    unsigned int v = ((unsigned int)u) << 16;
    return __builtin_bit_cast(float, v);
}

// exact-gelu via A&S 7.1.26 erf approx (|err|<=1.5e-7)
static __device__ __forceinline__ float gelu_f(float v) {
    float z = v * 0.70710678118654752f;
    float az = fabsf(z);
    float t = 1.0f / (1.0f + 0.3275911f * az);
    float poly = t * (0.254829592f + t * (-0.284496736f + t * (1.421413741f +
                 t * (-1.453152027f + t * 1.061405429f))));
    float erf_abs = 1.0f - poly * __expf(-az * az);
    float erf_v = (z < 0.f) ? -erf_abs : erf_abs;
    return 0.5f * v * (1.0f + erf_v);
}

static __device__ __forceinline__ void gll16(const void* g, void* l) {
    __builtin_amdgcn_global_load_lds((const __attribute__((address_space(1))) void*)g,
                                     (__attribute__((address_space(3))) void*)l, 16, 0, 0);
}

static __device__ __forceinline__ void barf() {
    __builtin_amdgcn_s_barrier();
    asm volatile("" ::: "memory");
}
#define LGKM0 asm volatile("s_waitcnt lgkmcnt(0)" ::: "memory")
#define VMC6  asm volatile("s_waitcnt vmcnt(6)" ::: "memory")
#define VMC0  asm volatile("s_waitcnt vmcnt(0)" ::: "memory")
#define PRIO1 __builtin_amdgcn_s_setprio(1)
#define PRIO0 __builtin_amdgcn_s_setprio(0)

// ---------------- small init ----------------
__global__ void init_small_kernel(int* counts, int* cursor, float* usage) {
    int i = threadIdx.x;
    if (i < 8) { counts[i] = 0; cursor[i] = 0; usage[i] = 0.f; }
}

// ---------------- fused transpose+convert for both weight sets ----------------
// fam 0: w1 [C,H] fp32 -> w1t [H,C] bf16 (R=C, S=H); fam 1: w2 [H,C] -> w2t [C,H]
// 64x64 tile; float4 loads, ushort4 stores. 16384 blocks total.
__global__ __launch_bounds__(256) void transpose_cvt_kernel(
    const float* __restrict__ w1, const float* __restrict__ w1s,
    const float* __restrict__ w2, const float* __restrict__ w2s,
    __hip_bfloat16* __restrict__ w1t, __hip_bfloat16* __restrict__ w2t)
{
    int bid = blockIdx.x;
    int fam = bid >> 13;
    int r = bid & 8191;
    int e = r >> 10;
    int t_ = r & 1023;
    int R, S, s0, r0;
    const float* src; unsigned short* d;
    if (fam == 0) {
        R = C_DIM; S = H_DIM;
        src = (e < NEXP) ? (w1 + (size_t)e * R * S) : w1s;
        d = (unsigned short*)(w1t) + (size_t)e * R * S;
        s0 = (t_ & 63) * 64; r0 = (t_ >> 6) * 64;
    } else {
        R = H_DIM; S = C_DIM;
        src = (e < NEXP) ? (w2 + (size_t)e * R * S) : w2s;
        d = (unsigned short*)(w2t) + (size_t)e * R * S;
        s0 = (t_ & 15) * 64; r0 = (t_ >> 4) * 64;
    }
    __shared__ float t[64][65];
    int lx = (threadIdx.x & 15) * 4, ty = threadIdx.x >> 4;   // 16 x 16
#pragma unroll
    for (int i = 0; i < 4; i++) {
        int rr = ty + i * 16;
        float4 v = *(const float4*)(src + (size_t)(r0 + rr) * S + s0 + lx);
        t[rr][lx] = v.x; t[rr][lx + 1] = v.y; t[rr][lx + 2] = v.z; t[rr][lx + 3] = v.w;
    }
    __syncthreads();
#pragma unroll
    for (int i = 0; i < 4; i++) {
        int ss = ty + i * 16;
        ushort4 o;
        o.x = f2bf(t[lx][ss]); o.y = f2bf(t[lx + 1][ss]);
        o.z = f2bf(t[lx + 2][ss]); o.w = f2bf(t[lx + 3][ss]);
        *(ushort4*)(d + (size_t)(s0 + ss) * R + r0 + lx) = o;
    }
}

// ---------------- gating (fused x fp32->bf16 convert): one wave per token ----------------
__global__ __launch_bounds__(256) void gate_kernel(
    const float* __restrict__ x, const float* __restrict__ gw,
    unsigned short* __restrict__ xb,
    int* __restrict__ topki, float* __restrict__ topkw,
    int* counts, float* usage)
{
    int wid = threadIdx.x >> 6, lane = threadIdx.x & 63;
    int t = blockIdx.x * 4 + wid;
    float s[NEXP];
#pragma unroll
    for (int e = 0; e < NEXP; e++) s[e] = 0.f;
#pragma unroll
    for (int it = 0; it < 4; ++it) {
        int c = it * 256 + lane * 4;
        float4 xv = *(const float4*)(x + (size_t)t * C_DIM + c);
        ushort4 o;
        o.x = f2bf(xv.x); o.y = f2bf(xv.y); o.z = f2bf(xv.z); o.w = f2bf(xv.w);
        *(ushort4*)(xb + (size_t)t * C_DIM + c) = o;
        const float* g0 = gw + (size_t)c * NEXP;
#pragma unroll
        for (int e = 0; e < NEXP; e++) s[e] += xv.x * g0[e];
#pragma unroll
        for (int e = 0; e < NEXP; e++) s[e] += xv.y * g0[NEXP + e];
#pragma unroll
        for (int e = 0; e < NEXP; e++) s[e] += xv.z * g0[2 * NEXP + e];
#pragma unroll
        for (int e = 0; e < NEXP; e++) s[e] += xv.w * g0[3 * NEXP + e];
    }
#pragma unroll
    for (int e = 0; e < NEXP; e++)
        for (int off = 32; off > 0; off >>= 1) s[e] += __shfl_xor(s[e], off);
    if (lane == 0) {
        int e0 = 0;
        for (int e = 1; e < NEXP; e++) if (s[e] > s[e0]) e0 = e;
        int e1 = -1;
        for (int e = 0; e < NEXP; e++) {
            if (e == e0) continue;
            if (e1 < 0 || s[e] > s[e1]) e1 = e;
        }
        float w0 = 1.f / (1.f + expf(s[e1] - s[e0]));
        float w1 = 1.f - w0;
        topki[t * 2] = e0; topki[t * 2 + 1] = e1;
        topkw[t * 2] = w0; topkw[t * 2 + 1] = w1;
        atomicAdd(&counts[e0], 1); atomicAdd(&counts[e1], 1);
        atomicAdd(&usage[e0], w0); atomicAdd(&usage[e1], w1);
    }
}

// ---------------- prefix: group bases, pads, static entries, aux loss ----------------
__global__ __launch_bounds__(256) void prefix_kernel(
    const int* counts, const float* usage,
    int* base, int* pcount, int* cnt8,
    int* etok, float* ewt, float* y, int aux_index)
{
    __shared__ int sb[NGRP], sc[NGRP], sp[NGRP];
    if (threadIdx.x == 0) {
        int run = 0;
        for (int g = 0; g < NEXP; g++) {
            int c = counts[g];
            int p = (c + 127) & ~127;
            base[g] = run; pcount[g] = p; cnt8[g] = c;
            sb[g] = run; sc[g] = c; sp[g] = p;
            run += p;
        }
        base[NEXP] = run; pcount[NEXP] = N_TOK; cnt8[NEXP] = N_TOK;
        sb[NEXP] = run; sc[NEXP] = N_TOK; sp[NEXP] = N_TOK;
        float u[NEXP]; float mean = 0.f;
        for (int e = 0; e < NEXP; e++) { u[e] = usage[e] / (float)N_TOK; mean += u[e]; }
        mean /= (float)NEXP;
        float var = 0.f;
        for (int e = 0; e < NEXP; e++) { float dd = u[e] - mean; var += dd * dd; }
        var /= (float)NEXP;
        y[aux_index] = 0.01f * var;
    }
    __syncthreads();
    for (int i = threadIdx.x; i < N_TOK; i += 256) {
        etok[sb[NEXP] + i] = i; ewt[sb[NEXP] + i] = 1.0f;
    }
    for (int g = 0; g < NEXP; g++) {
        for (int i = sc[g] + (int)threadIdx.x; i < sp[g]; i += 256) {
            etok[sb[g] + i] = 0; ewt[sb[g] + i] = 0.f;
        }
    }
}

// ---------------- scatter into compact entry lists (+ inverse map) ----------------
__global__ void scatter_kernel(const int* __restrict__ topki, const float* __restrict__ topkw,
                               const int* __restrict__ base, int* cursor,
                               int* __restrict__ etok, float* __restrict__ ewt,
                               int* __restrict__ eidx)
{
    int i = blockIdx.x * 256 + threadIdx.x;   // < 8192
    int t = i >> 1;
    int e = topki[i];
    float w = topkw[i];
    int pos = atomicAdd(&cursor[e], 1);
    int idx = base[e] + pos;
    etok[idx] = t; ewt[idx] = w;
    eidx[i] = idx;
}

// =====================================================================
// 8-phase grouped GEMM core. Tile 256x256, BK=64, 512 thr (8 waves,
// 2M x 4N), per-wave 128x64. LDS 128KB, 2 dbufs. 4 quadrant phases per
// K-tile; counted vmcnt(6) once per K-tile. Phase: {reads (plain C++
// ds_read_b128, B before A); stage (gll16); barrier; setprio(1); 16 MFMA
// with COMPILER fine-grained lgkm waits; setprio(0); lgkmcnt(0);
// barrier}.  The trailing lgkmcnt(0) (nearly free at runtime) upholds
// the invariant "my reads retired before I pass the end barrier", so the
// next phase's global_load_lds writes cannot corrupt an in-flight read
// (rule-#18 class hazard) even if the compiler sinks register-only MFMAs
// past the barrier (harmless).  Last two K-tiles peeled: NKT-2 ends with
// vmcnt(0)+barrier (all slices of last buffer resident), final tile runs
// barrier-free.  Source chunk XOR swizzle -> 0 bank conflicts.
// =====================================================================

static __device__ __forceinline__ void mfma16(const short8 (&a)[8], const short8 (&b)[4],
                                              floatx4 (&acc)[8][4], int mo, int no) {
#pragma unroll
    for (int i = 0; i < 4; i++)
#pragma unroll
        for (int j = 0; j < 2; j++)
#pragma unroll
            for (int kk = 0; kk < 2; kk++)
                acc[mo + i][no + j] = __builtin_amdgcn_mfma_f32_16x16x32_bf16(
                    a[i * 2 + kk], b[j * 2 + kk], acc[mo + i][no + j], 0, 0, 0);
}
static __device__ __forceinline__ void rdA(short8 (&d)[8], const char* b, int sw0, int sw1) {
#pragma unroll
    for (int i = 0; i < 4; i++) {
        d[i * 2]     = *(const short8*)(b + i * 2048 + sw0);
        d[i * 2 + 1] = *(const short8*)(b + i * 2048 + sw1);
    }
}
static __device__ __forceinline__ void rdB(short8 (&d)[4], const char* b, int sw0, int sw1) {
#pragma unroll
    for (int j = 0; j < 2; j++) {
        d[j * 2]     = *(const short8*)(b + j * 2048 + sw0);
        d[j * 2 + 1] = *(const short8*)(b + j * 2048 + sw1);
    }
}

static __device__ __forceinline__ void gemm_core(char* lds, int NKT,
    const char* pA0, const char* pA1, const char* pA2, const char* pA3,
    const char* pB0, const char* pB1, const char* pB2, const char* pB3,
    floatx4 (&acc)[8][4])
{
    int tid = threadIdx.x, lane = tid & 63, w = tid >> 6;
    int wm = w >> 2, wn = w & 3, l16 = lane & 15, quad = lane >> 4;
    int sw0 = ((quad ^ (l16 & 7)) << 4);
    int sw1 = (((4 + quad) ^ (l16 & 7)) << 4);
    int aoff = (wm * 64 + l16) * 128;
    int boff = (wn * 32 + l16) * 128;
    int wb = w * 1024;
    short8 aM0[8], aM1[8], bN0[4], bN1[4];

#define SA_(h, doff, ko) do { \
    gll16(((h) ? pA1 : pA0) + (ko), lds + (doff) + (h) * 16384 + wb); \
    gll16(((h) ? pA3 : pA2) + (ko), lds + (doff) + (h) * 16384 + 8192 + wb); } while (0)
#define SB_(nh, doff, ko) do { \
    gll16(((nh) ? pB1 : pB0) + (ko), lds + 65536 + (doff) + (nh) * 16384 + wb); \
    gll16(((nh) ? pB3 : pB2) + (ko), lds + 65536 + (doff) + (nh) * 16384 + 8192 + wb); } while (0)

    // prologue: Kt0 full (dbuf0) + Kt1 {Ah0,Ah1,Bn0} (dbuf1)
    SA_(0, 0, 0); SA_(1, 0, 0); SB_(0, 0, 0); SB_(1, 0, 0);
    SA_(0, 32768, 128); SA_(1, 32768, 128); SB_(0, 32768, 128);
    VMC6;          // Kt0's 4 units retired; 3 in flight
    barf();

#pragma unroll 1
    for (int T = 0; T < NKT - 2; ++T) {
        int curo = (T & 1) << 15;
        int nxto = curo ^ 32768;
        // ---- q0 (M0,N0) ----
        rdB(bN0, lds + 65536 + curo + boff, sw0, sw1);
        rdA(aM0, lds + curo + aoff, sw0, sw1);
        SB_(1, nxto, 128);
        barf();
        PRIO1; mfma16(aM0, bN0, acc, 0, 0); PRIO0;
        LGKM0; barf();
        // ---- q1 (M1,N0) ----
        rdA(aM1, lds + curo + 16384 + aoff, sw0, sw1);
        SA_(0, curo, 256);
        barf();
        PRIO1; mfma16(aM1, bN0, acc, 4, 0); PRIO0;
        LGKM0; barf();
        // ---- q2 (M0,N1) ----
        rdB(bN1, lds + 65536 + curo + 16384 + boff, sw0, sw1);
        SA_(1, curo, 256);
        barf();
        PRIO1; mfma16(aM0, bN1, acc, 0, 2); PRIO0;
        LGKM0; barf();
        // ---- q3 (M1,N1) ----
        SB_(0, curo, 256);
        barf();
        PRIO1; mfma16(aM1, bN1, acc, 4, 2); PRIO0;
        VMC6;
        barf();
        pA0 += 128; pA1 += 128; pA2 += 128; pA3 += 128;
        pB0 += 128; pB1 += 128; pB2 += 128; pB3 += 128;
    }
    // ---- T = NKT-2 (stages only B-n1 of the last tile) ----
    {
        int curo = ((NKT - 2) & 1) << 15;
        int nxto = curo ^ 32768;
        rdB(bN0, lds + 65536 + curo + boff, sw0, sw1);
        rdA(aM0, lds + curo + aoff, sw0, sw1);
        SB_(1, nxto, 128);
        barf();
        PRIO1; mfma16(aM0, bN0, acc, 0, 0); PRIO0;
        LGKM0; barf();
        rdA(aM1, lds + curo + 16384 + aoff, sw0, sw1);
        barf();
        PRIO1; mfma16(aM1, bN0, acc, 4, 0); PRIO0;
        LGKM0; barf();
        rdB(bN1, lds + 65536 + curo + 16384 + boff, sw0, sw1);
        barf();
        PRIO1; mfma16(aM0, bN1, acc, 0, 2); PRIO0;
        LGKM0; barf();
        PRIO1; mfma16(aM1, bN1, acc, 4, 2); PRIO0;
        VMC0;           // all slices of last-tile buffer resident after barrier
        barf();
        // ---- T = NKT-1: barrier-free (no further LDS writes) ----
        int lasto = nxto;
        rdB(bN0, lds + 65536 + lasto + boff, sw0, sw1);
        rdA(aM0, lds + lasto + aoff, sw0, sw1);
        rdA(aM1, lds + lasto + 16384 + aoff, sw0, sw1);
        rdB(bN1, lds + 65536 + lasto + 16384 + boff, sw0, sw1);
        mfma16(aM0, bN0, acc, 0, 0);
        mfma16(aM1, bN0, acc, 4, 0);
        mfma16(aM0, bN1, acc, 0, 2);
        mfma16(aM1, bN1, acc, 4, 2);
    }
#undef SA_
#undef SB_
}

// ---------------- grouped GEMM1: h = gelu(X @ W1[g]) ----------------
// grid: 4096 = 8 xcd * 16 ct * 32 s; xcd = (g+mt)&7 balanced swizzle.
__global__ __launch_bounds__(512, 2) void gemm1_kernel(
    const __hip_bfloat16* __restrict__ xb,
    const __hip_bfloat16* __restrict__ w1t,   // [8][H][C]
    __hip_bfloat16* __restrict__ h,           // [HCAP][H]
    const int* __restrict__ etok,
    const int* __restrict__ base,
    const int* __restrict__ pcount)
{
    int id = blockIdx.x;
    int xcd = id & 7, rest = id >> 3;
    int ct = rest & 15, s = rest >> 4;        // s in [0,32)
    int g = s & 7;
    int mt = ((xcd - g) & 7) + 8 * (s >> 3);
    int psz = pcount[g];
    if (mt * 256 >= psz) return;
    int eb = base[g];

    __shared__ __align__(16) char lds[131072];

    int tid = threadIdx.x, lane = tid & 63, w = tid >> 6;
    int u0 = 8 * w + (lane >> 3);                      // staging unit row [0,64)
    int v  = (u0 & 31) + ((u0 >> 5) << 6);             // B row helper
    int ssw = ((lane & 7) ^ (lane >> 3)) * 16;         // source chunk swizzle (bytes)

    int t0 = etok[eb + mt * 256 + u0];
    int t1 = etok[eb + mt * 256 + 64 + u0];
    int t2 = etok[eb + mt * 256 + 128 + u0];
    int t3 = etok[eb + mt * 256 + 192 + u0];
    const char* pA0 = (const char*)(xb + (size_t)t0 * C_DIM) + ssw;
    const char* pA1 = (const char*)(xb + (size_t)t1 * C_DIM) + ssw;
    const char* pA2 = (const char*)(xb + (size_t)t2 * C_DIM) + ssw;
    const char* pA3 = (const char*)(xb + (size_t)t3 * C_DIM) + ssw;
    const char* pB0 = (const char*)(w1t + ((size_t)g * H_DIM + ct * 256 + v) * C_DIM) + ssw;
    const char* pB1 = (const char*)(w1t + ((size_t)g * H_DIM + ct * 256 + v + 32) * C_DIM) + ssw;
    const char* pB2 = (const char*)(w1t + ((size_t)g * H_DIM + ct * 256 + v + 128) * C_DIM) + ssw;
    const char* pB3 = (const char*)(w1t + ((size_t)g * H_DIM + ct * 256 + v + 160) * C_DIM) + ssw;

    floatx4 acc[8][4] = {};
    gemm_core(lds, C_DIM / 64, pA0, pA1, pA2, pA3, pB0, pB1, pB2, pB3, acc);

    int wm = w >> 2, wn = w & 3, l16 = lane & 15, quad = lane >> 4;
#pragma unroll
    for (int i = 0; i < 8; i++) {
        int lr0 = mt * 256 + wm * 128 + i * 16 + quad * 4;
#pragma unroll
        for (int reg = 0; reg < 4; reg++) {
            int lr = lr0 + reg;
            if (lr < psz) {
                size_t hrow = (size_t)(eb + lr) * H_DIM;
#pragma unroll
                for (int j = 0; j < 4; j++) {
                    int cc = ct * 256 + wn * 64 + j * 16 + l16;
                    h[hrow + cc] = __float2bfloat16(gelu_f(acc[i][j][reg]));
                }
            }
        }
    }
}

// ---------------- grouped GEMM2: yp[entry] = H[entry] @ W2[g] ----------------
// grid: 1024 = 8 xcd * 4 ct * 32 s; ct-blocks of one A-panel co-locate on
// one XCD -> L2 reuse of h.
__global__ __launch_bounds__(512, 2) void gemm2_kernel(
    const __hip_bfloat16* __restrict__ h,
    const __hip_bfloat16* __restrict__ w2t,   // [8][C][H]
    unsigned short* __restrict__ yp,          // bf16 [HCAP][C]
    const int* __restrict__ base,
    const int* __restrict__ pcount)
{
    int id = blockIdx.x;
    int xcd = id & 7, rest = id >> 3;
    int ct = rest & 3, s = rest >> 2;         // s in [0,32)
    int g = s & 7;
    int mt = ((xcd - g) & 7) + 8 * (s >> 3);
    int psz = pcount[g];
    if (mt * 256 >= psz) return;
    int eb = base[g];

    __shared__ __align__(16) char lds[131072];

    int tid = threadIdx.x, lane = tid & 63, w = tid >> 6;
    int u0 = 8 * w + (lane >> 3);
    int v  = (u0 & 31) + ((u0 >> 5) << 6);
    int ssw = ((lane & 7) ^ (lane >> 3)) * 16;

    const char* pA0 = (const char*)(h + (size_t)(eb + mt * 256 + u0) * H_DIM) + ssw;
    const char* pA1 = (const char*)(h + (size_t)(eb + mt * 256 + 64 + u0) * H_DIM) + ssw;
    const char* pA2 = (const char*)(h + (size_t)(eb + mt * 256 + 128 + u0) * H_DIM) + ssw;
    const char* pA3 = (const char*)(h + (size_t)(eb + mt * 256 + 192 + u0) * H_DIM) + ssw;
    const char* pB0 = (const char*)(w2t + ((size_t)g * C_DIM + ct * 256 + v) * H_DIM) + ssw;
    const char* pB1 = (const char*)(w2t + ((size_t)g * C_DIM + ct * 256 + v + 32) * H_DIM) + ssw;
    const char* pB2 = (const char*)(w2t + ((size_t)g * C_DIM + ct * 256 + v + 128) * H_DIM) + ssw;
    const char* pB3 = (const char*)(w2t + ((size_t)g * C_DIM + ct * 256 + v + 160) * H_DIM) + ssw;

    floatx4 acc[8][4] = {};
    gemm_core(lds, H_DIM / 64, pA0, pA1, pA2, pA3, pB0, pB1, pB2, pB3, acc);

    int wm = w >> 2, wn = w & 3, l16 = lane & 15, quad = lane >> 4;
#pragma unroll
    for (int i = 0; i < 8; i++) {
        int lr0 = mt * 256 + wm * 128 + i * 16 + quad * 4;
#pragma unroll
        for (int reg = 0; reg < 4; reg++) {
            int lr = lr0 + reg;
            if (lr < psz) {
                size_t yrow = (size_t)(eb + lr) * C_DIM;
#pragma unroll
                for (int j = 0; j < 4; j++) {
                    int cc = ct * 256 + wn * 64 + j * 16 + l16;
                    yp[yrow + cc] = f2bf(acc[i][j][reg]);
                }
            }
        }
    }
}

// ---------------- combine: y[t] = w0*yp[i0] + w1*yp[i1] + yp[static+t] ----------------
__global__ __launch_bounds__(256) void combine_kernel(
    const unsigned short* __restrict__ yp,
    const int* __restrict__ eidx,
    const float* __restrict__ topkw,
    const int* __restrict__ base,
    float* __restrict__ y)
{
    int t = blockIdx.x;
    int i0 = eidx[t * 2], i1 = eidx[t * 2 + 1];
    float w0 = topkw[t * 2], w1 = topkw[t * 2 + 1];
    int is = base[NEXP] + t;
    int c = threadIdx.x * 4;
    ushort4 a = *(const ushort4*)(yp + (size_t)i0 * C_DIM + c);
    ushort4 b = *(const ushort4*)(yp + (size_t)i1 * C_DIM + c);
    ushort4 s = *(const ushort4*)(yp + (size_t)is * C_DIM + c);
    float4 o;
    o.x = w0 * bf2f(a.x) + w1 * bf2f(b.x) + bf2f(s.x);
    o.y = w0 * bf2f(a.y) + w1 * bf2f(b.y) + bf2f(s.y);
    o.z = w0 * bf2f(a.z) + w1 * bf2f(b.z) + bf2f(s.z);
    o.w = w0 * bf2f(a.w) + w1 * bf2f(b.w) + bf2f(s.w);
    *(float4*)(y + (size_t)t * C_DIM + c) = o;
}

extern "C" void kernel_launch(void* const* d_in, const int* in_sizes, int n_in,
                              void* d_out, int out_size, void* d_ws, size_t ws_size,
                              hipStream_t stream) {
    const float* x      = (const float*)d_in[0];
    const float* gate_w = (const float*)d_in[1];
    const float* w1     = (const float*)d_in[2];
    const float* w2     = (const float*)d_in[3];
    const float* w1s    = (const float*)d_in[4];
    const float* w2s    = (const float*)d_in[5];
    float* y = (float*)d_out;
    char* ws = (char*)d_ws;

    int*   counts = (int*)(ws + OFF_COUNTS);
    int*   cursor = (int*)(ws + OFF_CURSOR);
    int*   base   = (int*)(ws + OFF_BASE);
    int*   pcount = (int*)(ws + OFF_PCOUNT);
    int*   cnt8   = (int*)(ws + OFF_CNT8);
    float* usage  = (float*)(ws + OFF_USAGE);
    int*   topki  = (int*)(ws + OFF_TOPKI);
    float* topkw  = (float*)(ws + OFF_TOPKW);
    int*   etok   = (int*)(ws + OFF_ETOK);
    float* ewt    = (float*)(ws + OFF_EWT);
    int*   eidx   = (int*)(ws + OFF_EIDX);
    unsigned short* xb_u = (unsigned short*)(ws + OFF_XB);
    __hip_bfloat16* xb  = (__hip_bfloat16*)(ws + OFF_XB);
    __hip_bfloat16* w1t = (__hip_bfloat16*)(ws + OFF_W1T);
    __hip_bfloat16* w2t = (__hip_bfloat16*)(ws + OFF_W2T);
    __hip_bfloat16* hbuf = (__hip_bfloat16*)(ws + OFF_H);
    unsigned short* yp  = (unsigned short*)(ws + OFF_W1T);  // aliases w1t (dead after gemm1)

    init_small_kernel<<<1, 64, 0, stream>>>(counts, cursor, usage);

    transpose_cvt_kernel<<<16384, 256, 0, stream>>>(w1, w1s, w2, w2s, w1t, w2t);

    gate_kernel<<<N_TOK / 4, 256, 0, stream>>>(x, gate_w, xb_u, topki, topkw, counts, usage);
    prefix_kernel<<<1, 256, 0, stream>>>(counts, usage, base, pcount, cnt8, etok, ewt, y, N_TOK * C_DIM);
    scatter_kernel<<<(N_TOK * 2) / 256, 256, 0, stream>>>(topki, topkw, base, cursor, etok, ewt, eidx);

    gemm1_kernel<<<4096, 512, 0, stream>>>(xb, w1t, hbuf, etok, base, pcount);
    gemm2_kernel<<<1024, 512, 0, stream>>>(hbuf, w2t, yp, base, pcount);
    combine_kernel<<<N_TOK, 256, 0, stream>>>(yp, eidx, topkw, base, y);
}